// Round 1
// baseline (88.281 us; speedup 1.0000x reference)
//
#include <hip/hip_runtime.h>
#include <math.h>

// 9-qubit statevector sim, one wave (64 lanes) per simulation.
// Qubits 0..5 -> lane bits 0..5 (cross-lane via shfl_xor).
// Qubits 6..8 -> register bits 0..2 (8 complex amps per lane).
// B=8, Cch=4, fx=fy=28 -> 25088 sims. Output (8,30,30,4) fp32, zero border.

#define PI_F 3.14159265358979f

__device__ __forceinline__ float sxor(float v, int mask) {
    return __shfl_xor(v, mask, 64);
}

// --- CRZ: ctrl & tgt are lane bits -------------------------------------
template<int C, int T>
__device__ __forceinline__ void crz_ll(float (&ar)[8], float (&ai)[8], int lane, float h) {
    float sz, cz; __sincosf(h, &sz, &cz);
    bool cb = (lane >> C) & 1;
    bool tb = (lane >> T) & 1;
    float er = cb ? cz : 1.0f;
    float ei = cb ? (tb ? sz : -sz) : 0.0f;
#pragma unroll
    for (int r = 0; r < 8; ++r) {
        float nr = ar[r] * er - ai[r] * ei;
        float ni = ar[r] * ei + ai[r] * er;
        ar[r] = nr; ai[r] = ni;
    }
}

// --- CRZ: ctrl = qubit6 (reg bit0), tgt = qubit4 (lane bit4) ----------
__device__ __forceinline__ void crz_64(float (&ar)[8], float (&ai)[8], int lane, float h) {
    float sz, cz; __sincosf(h, &sz, &cz);
    float ei = ((lane >> 4) & 1) ? sz : -sz;
#pragma unroll
    for (int r = 1; r < 8; r += 2) {   // reg bit0 set -> ctrl = 1
        float nr = ar[r] * cz - ai[r] * ei;
        float ni = ar[r] * ei + ai[r] * cz;
        ar[r] = nr; ai[r] = ni;
    }
}

// --- CRZ: ctrl & tgt are reg bits --------------------------------------
template<int CB, int TB>
__device__ __forceinline__ void crz_rr(float (&ar)[8], float (&ai)[8], float h) {
    float sz, cz; __sincosf(h, &sz, &cz);
#pragma unroll
    for (int r = 0; r < 8; ++r) {
        if (!((r >> CB) & 1)) continue;
        float ei = ((r >> TB) & 1) ? sz : -sz;
        float nr = ar[r] * cz - ai[r] * ei;
        float ni = ar[r] * ei + ai[r] * cz;
        ar[r] = nr; ai[r] = ni;
    }
}

// --- CRX: ctrl & tgt are lane bits -------------------------------------
// RX matrix is symmetric: new = c*self - i*s*partner, lane-uniform.
template<int C, int T>
__device__ __forceinline__ void crx_ll(float (&ar)[8], float (&ai)[8], int lane, float h) {
    float s, c; __sincosf(h, &s, &c);
    bool cb = (lane >> C) & 1;
#pragma unroll
    for (int r = 0; r < 8; ++r) {
        float pr = sxor(ar[r], 1 << T);
        float pi_ = sxor(ai[r], 1 << T);
        float nr = c * ar[r] + s * pi_;
        float ni = c * ai[r] - s * pr;
        ar[r] = cb ? nr : ar[r];
        ai[r] = cb ? ni : ai[r];
    }
}

// --- CRX: ctrl = qubit6 (reg bit0), tgt = qubit4 (lane bit4) ----------
__device__ __forceinline__ void crx_64(float (&ar)[8], float (&ai)[8], float h) {
    float s, c; __sincosf(h, &s, &c);
#pragma unroll
    for (int r = 1; r < 8; r += 2) {
        float pr = sxor(ar[r], 16);
        float pi_ = sxor(ai[r], 16);
        float nr = c * ar[r] + s * pi_;
        float ni = c * ai[r] - s * pr;
        ar[r] = nr; ai[r] = ni;
    }
}

// --- CRX: ctrl & tgt are reg bits --------------------------------------
template<int CB, int TB>
__device__ __forceinline__ void crx_rr(float (&ar)[8], float (&ai)[8], float h) {
    float s, c; __sincosf(h, &s, &c);
#pragma unroll
    for (int r0 = 0; r0 < 8; ++r0) {
        if (!((r0 >> CB) & 1)) continue;  // ctrl must be set
        if ((r0 >> TB) & 1) continue;     // r0 is tgt=0 side
        int r1 = r0 | (1 << TB);
        float s0r = ar[r0], s0i = ai[r0], s1r = ar[r1], s1i = ai[r1];
        ar[r0] = c * s0r + s * s1i;  ai[r0] = c * s0i - s * s1r;
        ar[r1] = c * s1r + s * s0i;  ai[r1] = c * s1i - s * s0r;
    }
}

__global__ void zero_kernel(float* __restrict__ out, int n) {
    int t = blockIdx.x * blockDim.x + threadIdx.x;
    if (t < n) out[t] = 0.0f;
}

__global__ __launch_bounds__(256) void quanv_kernel(
    const float* __restrict__ x,   // (8,30,30,3)
    const float* __restrict__ qp,  // (4,16)
    float* __restrict__ out)       // (8,30,30,4)
{
    const int tid = blockIdx.x * blockDim.x + threadIdx.x;
    const int wave = tid >> 6;
    const int lane = tid & 63;
    if (wave >= 25088) return;

    // sim index = ((b*4 + ch)*28 + i)*28 + j
    int j = wave % 28;
    int t1 = wave / 28;
    int i = t1 % 28;
    int t2 = t1 / 28;
    int ch = t2 & 3;
    int b  = t2 >> 2;

    // --- angles (wave-uniform) ---
    float hq[9];
#pragma unroll
    for (int q = 0; q < 9; ++q) {
        int y = i + q / 3, xx = j + q % 3;
        const float* p = x + (((b * 30 + y) * 30) + xx) * 3;
        float avg = (p[0] + p[1] + p[2]) * (1.0f / 3.0f);
        // t = 2*pi*avg - pi ; h = t/2
        hq[q] = PI_F * avg - 0.5f * PI_F;
    }
    float th[16];
#pragma unroll
    for (int k = 0; k < 16; ++k) th[k] = 0.5f * qp[ch * 16 + k];

    // --- state |0..0> ---
    float ar[8], ai[8];
#pragma unroll
    for (int r = 0; r < 8; ++r) { ar[r] = 0.0f; ai[r] = 0.0f; }
    if (lane == 0) ar[0] = 1.0f;

    // --- initial RX on every qubit ---
#pragma unroll
    for (int q = 0; q < 6; ++q) {          // lane-bit qubits
        float s, c; __sincosf(hq[q], &s, &c);
#pragma unroll
        for (int r = 0; r < 8; ++r) {
            float pr = sxor(ar[r], 1 << q);
            float pi_ = sxor(ai[r], 1 << q);
            float nr = c * ar[r] + s * pi_;
            float ni = c * ai[r] - s * pr;
            ar[r] = nr; ai[r] = ni;
        }
    }
#pragma unroll
    for (int q = 6; q < 9; ++q) {          // reg-bit qubits
        float s, c; __sincosf(hq[q], &s, &c);
        int bit = 1 << (q - 6);
#pragma unroll
        for (int r0 = 0; r0 < 8; ++r0) {
            if (r0 & bit) continue;
            int r1 = r0 | bit;
            float s0r = ar[r0], s0i = ai[r0], s1r = ar[r1], s1i = ai[r1];
            ar[r0] = c * s0r + s * s1i;  ai[r0] = c * s0i - s * s1r;
            ar[r1] = c * s1r + s * s0i;  ai[r1] = c * s1i - s * s0r;
        }
    }

    // --- PAIRS = (1,0),(3,2),(2,0),(8,7),(5,4),(7,6),(6,4),(4,0) ---
    // qubit->bit: 0..5 lane bits, 6->reg0, 7->reg1, 8->reg2
    crz_ll<1, 0>(ar, ai, lane, th[0]);   crx_ll<1, 0>(ar, ai, lane, th[1]);
    crz_ll<3, 2>(ar, ai, lane, th[2]);   crx_ll<3, 2>(ar, ai, lane, th[3]);
    crz_ll<2, 0>(ar, ai, lane, th[4]);   crx_ll<2, 0>(ar, ai, lane, th[5]);
    crz_rr<2, 1>(ar, ai, th[6]);         crx_rr<2, 1>(ar, ai, th[7]);    // (8,7)
    crz_ll<5, 4>(ar, ai, lane, th[8]);   crx_ll<5, 4>(ar, ai, lane, th[9]);
    crz_rr<1, 0>(ar, ai, th[10]);        crx_rr<1, 0>(ar, ai, th[11]);   // (7,6)
    crz_64(ar, ai, lane, th[12]);        crx_64(ar, ai, th[13]);         // (6,4)
    crz_ll<4, 0>(ar, ai, lane, th[14]);  crx_ll<4, 0>(ar, ai, lane, th[15]);

    // --- measurement: z = sum_{q0=0}|a|^2 - sum_{q0=1}|a|^2 ; q0 = lane bit0
    float z = 0.0f;
#pragma unroll
    for (int r = 0; r < 8; ++r) z += ar[r] * ar[r] + ai[r] * ai[r];
    z = (lane & 1) ? -z : z;
#pragma unroll
    for (int m = 1; m < 64; m <<= 1) z += sxor(z, m);

    if (lane == 0) {
        // out[b, i+1, j+1, ch]
        out[((b * 30 + (i + 1)) * 30 + (j + 1)) * 4 + ch] = (z + 1.0f) * 0.5f;
    }
}

extern "C" void kernel_launch(void* const* d_in, const int* in_sizes, int n_in,
                              void* d_out, int out_size, void* d_ws, size_t ws_size,
                              hipStream_t stream) {
    const float* x  = (const float*)d_in[0];   // (8,30,30,3) fp32
    const float* qp = (const float*)d_in[1];   // (4,16) fp32
    float* out = (float*)d_out;                // (8,30,30,4) fp32

    zero_kernel<<<(out_size + 255) / 256, 256, 0, stream>>>(out, out_size);

    // 25088 sims * 64 lanes / 256 threads per block = 6272 blocks
    quanv_kernel<<<6272, 256, 0, stream>>>(x, qp, out);
}

// Round 2
// 85.042 us; speedup vs baseline: 1.0381x; 1.0381x over previous
//
#include <hip/hip_runtime.h>
#include <math.h>

// 9-qubit statevector sim, one wave (64 lanes) per simulation.
// Qubit->bit mapping chosen so CRX targets are register bits where possible:
//   reg  bit 0 = qubit 0, reg  bit 1 = qubit 2, reg  bit 2 = qubit 4
//   lane bit 0 = qubit 1, lane bit 1 = qubit 3, lane bit 2 = qubit 5,
//   lane bit 3 = qubit 6, lane bit 4 = qubit 7, lane bit 5 = qubit 8
// Initial 9 RX on |0..0> = product state -> direct per-amp init, no gates.
// Only pairs (8,7) and (7,6) are lane-lane CRX (the only shuffled gates).

#define PI_F 3.14159265358979f

__device__ __forceinline__ float sxor(float v, int m) { return __shfl_xor(v, m, 64); }

#define CMUL(ar_, ai_, er_, ei_) { float _nr = (ar_)*(er_) - (ai_)*(ei_); \
                                   (ai_) = (ar_)*(ei_) + (ai_)*(er_); (ar_) = _nr; }

// --- CRZ: ctrl = lane bit LC, tgt = reg bit TB ---
template<int LC, int TB>
__device__ __forceinline__ void crz_lr(float (&ar)[8], float (&ai)[8], int lane, float h) {
    float sz, cz; __sincosf(h, &sz, &cz);
    bool cb = (lane >> LC) & 1;
    float er  = cb ? cz  : 1.0f;
    float ei0 = cb ? -sz : 0.0f;   // tgt bit = 0 -> e^{-ih}
    float ei1 = cb ?  sz : 0.0f;   // tgt bit = 1 -> e^{+ih}
#pragma unroll
    for (int r = 0; r < 8; ++r) {
        float ei = ((r >> TB) & 1) ? ei1 : ei0;
        CMUL(ar[r], ai[r], er, ei);
    }
}

// --- CRX: ctrl = lane bit LC, tgt = reg bit TB ---
template<int LC, int TB>
__device__ __forceinline__ void crx_lr(float (&ar)[8], float (&ai)[8], int lane, float h) {
    float s, c; __sincosf(h, &s, &c);
    bool cb = (lane >> LC) & 1;
    float cc = cb ? c : 1.0f;      // ctrl=0 -> identity
    float ss = cb ? s : 0.0f;
#pragma unroll
    for (int r0 = 0; r0 < 8; ++r0) {
        if (r0 & (1 << TB)) continue;
        int r1 = r0 | (1 << TB);
        float s0r = ar[r0], s0i = ai[r0], s1r = ar[r1], s1i = ai[r1];
        ar[r0] = cc * s0r + ss * s1i;  ai[r0] = cc * s0i - ss * s1r;
        ar[r1] = cc * s1r + ss * s0i;  ai[r1] = cc * s1i - ss * s0r;
    }
}

// --- CRZ: ctrl = reg bit CB, tgt = reg bit TB ---
template<int CB, int TB>
__device__ __forceinline__ void crz_rr(float (&ar)[8], float (&ai)[8], float h) {
    float sz, cz; __sincosf(h, &sz, &cz);
#pragma unroll
    for (int r = 0; r < 8; ++r) {
        if (!((r >> CB) & 1)) continue;       // ctrl must be 1
        float ei = ((r >> TB) & 1) ? sz : -sz;
        CMUL(ar[r], ai[r], cz, ei);
    }
}

// --- CRX: ctrl = reg bit CB, tgt = reg bit TB ---
template<int CB, int TB>
__device__ __forceinline__ void crx_rr(float (&ar)[8], float (&ai)[8], float h) {
    float s, c; __sincosf(h, &s, &c);
#pragma unroll
    for (int r0 = 0; r0 < 8; ++r0) {
        if (!((r0 >> CB) & 1)) continue;      // ctrl must be 1
        if ((r0 >> TB) & 1) continue;         // r0 = tgt 0 side
        int r1 = r0 | (1 << TB);
        float s0r = ar[r0], s0i = ai[r0], s1r = ar[r1], s1i = ai[r1];
        ar[r0] = c * s0r + s * s1i;  ai[r0] = c * s0i - s * s1r;
        ar[r1] = c * s1r + s * s0i;  ai[r1] = c * s1i - s * s0r;
    }
}

// --- CRZ: ctrl = lane bit LC, tgt = lane bit LT ---
template<int LC, int LT>
__device__ __forceinline__ void crz_ll(float (&ar)[8], float (&ai)[8], int lane, float h) {
    float sz, cz; __sincosf(h, &sz, &cz);
    bool cb = (lane >> LC) & 1;
    bool tb = (lane >> LT) & 1;
    float er = cb ? cz : 1.0f;
    float ei = cb ? (tb ? sz : -sz) : 0.0f;
#pragma unroll
    for (int r = 0; r < 8; ++r) CMUL(ar[r], ai[r], er, ei);
}

// --- CRX: ctrl = lane bit LC, tgt = lane bit LT (the only shuffled gate) ---
template<int LC, int LT>
__device__ __forceinline__ void crx_ll(float (&ar)[8], float (&ai)[8], int lane, float h) {
    float s, c; __sincosf(h, &s, &c);
    bool cb = (lane >> LC) & 1;
    float cc = cb ? c : 1.0f;      // partner has same ctrl bit -> identity ok
    float ss = cb ? s : 0.0f;
#pragma unroll
    for (int r = 0; r < 8; ++r) {
        float pr  = sxor(ar[r], 1 << LT);
        float pi_ = sxor(ai[r], 1 << LT);
        float nr = cc * ar[r] + ss * pi_;
        float ni = cc * ai[r] - ss * pr;
        ar[r] = nr; ai[r] = ni;
    }
}

__global__ __launch_bounds__(256) void quanv_kernel(
    const float* __restrict__ x,   // (8,30,30,3)
    const float* __restrict__ qp,  // (4,16)
    float* __restrict__ out)       // (8,30,30,4)
{
    const int tid = blockIdx.x * 256 + threadIdx.x;

    // ---- fused border zeroing (3712 elements, disjoint from interior) ----
    if (tid < 3712) {
        int e = tid & 3;
        int cb_ = tid >> 2;          // 0..927
        int bb = cb_ / 116;
        int cell = cb_ - bb * 116;
        int y, xx;
        if (cell < 30)      { y = 0;         xx = cell; }
        else if (cell < 60) { y = 29;        xx = cell - 30; }
        else if (cell < 88) { xx = 0;        y = cell - 59; }
        else                { xx = 29;       y = cell - 87; }
        out[((bb * 30 + y) * 30 + xx) * 4 + e] = 0.0f;
    }

    const int wave = tid >> 6;     // grid is exact: 6272*4 = 25088 waves
    const int lane = tid & 63;

    int j  = wave % 28;
    int t1 = wave / 28;
    int i  = t1 % 28;
    int t2 = t1 / 28;
    int ch = t2 & 3;
    int b  = t2 >> 2;

    // --- per-qubit RX half-angles -> sin/cos (wave-uniform) ---
    float sq[9], cq[9];
#pragma unroll
    for (int q = 0; q < 9; ++q) {
        int y = i + q / 3, xx = j + q % 3;
        const float* p = x + (((b * 30 + y) * 30) + xx) * 3;
        float avg = (p[0] + p[1] + p[2]) * (1.0f / 3.0f);
        float hq = PI_F * avg - 0.5f * PI_F;       // (2*pi*avg - pi)/2
        __sincosf(hq, &sq[q], &cq[q]);
    }
    float th[16];
#pragma unroll
    for (int k = 0; k < 16; ++k) th[k] = 0.5f * qp[ch * 16 + k];

    // --- product-state init: amp(bits) = (prod mag) * (-i)^popcount ---
    float mlane = ((lane     ) & 1 ? sq[1] : cq[1]);
    mlane      *= ((lane >> 1) & 1 ? sq[3] : cq[3]);
    mlane      *= ((lane >> 2) & 1 ? sq[5] : cq[5]);
    mlane      *= ((lane >> 3) & 1 ? sq[6] : cq[6]);
    mlane      *= ((lane >> 4) & 1 ? sq[7] : cq[7]);
    mlane      *= ((lane >> 5) & 1 ? sq[8] : cq[8]);
    int plm = __popc(lane) & 3;
    float br = (plm == 0) ? 1.0f : ((plm == 2) ? -1.0f : 0.0f);
    float bi = (plm == 1) ? -1.0f : ((plm == 3) ? 1.0f : 0.0f);

    float ar[8], ai[8];
#pragma unroll
    for (int r = 0; r < 8; ++r) {
        float m = mlane * ((r & 1) ? sq[0] : cq[0])
                        * ((r & 2) ? sq[2] : cq[2])
                        * ((r & 4) ? sq[4] : cq[4]);
        const int pr = ((r & 1) + ((r >> 1) & 1) + ((r >> 2) & 1)) & 3;
        float phr, phi;
        if      (pr == 0) { phr =  br; phi =  bi; }
        else if (pr == 1) { phr =  bi; phi = -br; }
        else if (pr == 2) { phr = -br; phi = -bi; }
        else              { phr = -bi; phi =  br; }
        ar[r] = m * phr; ai[r] = m * phi;
    }

    // --- PAIRS: (1,0),(3,2),(2,0),(8,7),(5,4),(7,6),(6,4),(4,0) ---
    crz_lr<0, 0>(ar, ai, lane, th[0]);   crx_lr<0, 0>(ar, ai, lane, th[1]);   // (1,0)
    crz_lr<1, 1>(ar, ai, lane, th[2]);   crx_lr<1, 1>(ar, ai, lane, th[3]);   // (3,2)
    crz_rr<1, 0>(ar, ai, th[4]);         crx_rr<1, 0>(ar, ai, th[5]);         // (2,0)
    crz_ll<5, 4>(ar, ai, lane, th[6]);   crx_ll<5, 4>(ar, ai, lane, th[7]);   // (8,7)
    crz_lr<2, 2>(ar, ai, lane, th[8]);   crx_lr<2, 2>(ar, ai, lane, th[9]);   // (5,4)
    crz_ll<4, 3>(ar, ai, lane, th[10]);  crx_ll<4, 3>(ar, ai, lane, th[11]);  // (7,6)
    crz_lr<3, 2>(ar, ai, lane, th[12]);  crx_lr<3, 2>(ar, ai, lane, th[13]);  // (6,4)
    crz_rr<2, 0>(ar, ai, th[14]);        crx_rr<2, 0>(ar, ai, th[15]);        // (4,0)

    // --- measurement: qubit0 = reg bit 0 ---
    float z = 0.0f;
#pragma unroll
    for (int r = 0; r < 8; ++r) {
        float t = ar[r] * ar[r] + ai[r] * ai[r];
        z += (r & 1) ? -t : t;
    }
#pragma unroll
    for (int m = 1; m < 64; m <<= 1) z += sxor(z, m);

    if (lane == 0)
        out[((b * 30 + (i + 1)) * 30 + (j + 1)) * 4 + ch] = (z + 1.0f) * 0.5f;
}

extern "C" void kernel_launch(void* const* d_in, const int* in_sizes, int n_in,
                              void* d_out, int out_size, void* d_ws, size_t ws_size,
                              hipStream_t stream) {
    const float* x  = (const float*)d_in[0];   // (8,30,30,3) fp32
    const float* qp = (const float*)d_in[1];   // (4,16) fp32
    float* out = (float*)d_out;                // (8,30,30,4) fp32

    // 25088 sims * 64 lanes / 256 threads = 6272 blocks (exact)
    quanv_kernel<<<6272, 256, 0, stream>>>(x, qp, out);
}

// Round 3
// 55.095 us; speedup vs baseline: 1.6023x; 1.5436x over previous
//
#include <hip/hip_runtime.h>
#include <math.h>

// Exact analytic collapse of the 9-qubit circuit.
//
// PAIRS = (1,0),(3,2),(2,0),(8,7),(5,4),(7,6),(6,4),(4,0). Each control
// qubit is fresh/uncorrelated with its target when its gate fires, and is
// never used afterwards. For a controlled gate CU(c,t) with ctrl marginal
// P(c=1)=p and ctrl ⊥ tgt:  E[O_t] evolves as  rho_t <- (1-p) rho_t + p V rho_t V†
// (off-diagonal ctrl blocks never contribute to observables not involving c).
// CRZ(hz);CRX(hx) on the same ctrl compose: V = RX(hx) RZ(hz).
//
// So:  rho0 (qubit0) mixed by q1, then by q2 (whose p comes from the (3,2)
// block), rho4 mixed by q5 then by q6 (whose p chains through (8,7)->(7,6)),
// final (4,0) mixes U into rho0 with weight p1 = P(q4=1).
// z = 1 - 2[(1-p1) rho0_11 + p1 (U rho0 U†)_11];  out = (z+1)/2.

#define PI_F 3.14159265358979f

struct C { float r, i; };
__device__ __forceinline__ C cmul(C a, C b) { return { a.r*b.r - a.i*b.i, a.r*b.i + a.i*b.r }; }
__device__ __forceinline__ C cconj(C a)     { return { a.r, -a.i }; }
__device__ __forceinline__ C cadd(C a, C b) { return { a.r + b.r, a.i + b.i }; }
__device__ __forceinline__ C cscale(C a, float s) { return { a.r * s, a.i * s }; }

struct V22 { C m00, m01, m10, m11; };

// V = RX(2*hx) * RZ(2*hz)  (hx,hz are HALF-angles)
__device__ __forceinline__ V22 makeV(float hx, float hz) {
    float sa, ca; __sincosf(hx, &sa, &ca);
    float sb, cb; __sincosf(hz, &sb, &cb);
    V22 v;
    v.m00 = {  ca * cb, -ca * sb };   //  ca * e        , e = cb - i sb
    v.m01 = {  sa * sb, -sa * cb };   // -i sa * e*
    v.m10 = { -sa * sb, -sa * cb };   // -i sa * e
    v.m11 = {  ca * cb,  ca * sb };   //  ca * e*
    return v;
}

struct Rho { float a, d; C b; };  // [[a, b], [b*, d]], a,d real

__device__ __forceinline__ Rho den_pure(C x0, C x1) {
    Rho r;
    r.a = x0.r * x0.r + x0.i * x0.i;
    r.d = x1.r * x1.r + x1.i * x1.i;
    r.b = cmul(x0, cconj(x1));
    return r;
}

// chi = V * (c, -i s)^T   (pure RX state)
__device__ __forceinline__ void applyV_pure(const V22& v, float c, float s, C& x0, C& x1) {
    C p0 = { c, 0.0f }, p1 = { 0.0f, -s };
    x0 = cadd(cmul(v.m00, p0), cmul(v.m01, p1));
    x1 = cadd(cmul(v.m10, p0), cmul(v.m11, p1));
}

__device__ __forceinline__ Rho applyV_rho(const V22& v, const Rho& r) {
    C bc = cconj(r.b);
    C M00 = cadd(cscale(v.m00, r.a), cmul(v.m01, bc));
    C M01 = cadd(cmul(v.m00, r.b), cscale(v.m01, r.d));
    C M10 = cadd(cscale(v.m10, r.a), cmul(v.m11, bc));
    C M11 = cadd(cmul(v.m10, r.b), cscale(v.m11, r.d));
    Rho o;
    o.a = cmul(M00, cconj(v.m00)).r + cmul(M01, cconj(v.m01)).r;
    o.d = cmul(M10, cconj(v.m10)).r + cmul(M11, cconj(v.m11)).r;
    o.b = cadd(cmul(M00, cconj(v.m10)), cmul(M01, cconj(v.m11)));
    return o;
}

// (V rho V†)_11 only
__device__ __forceinline__ float rho11_after(const V22& v, const Rho& r) {
    C bc = cconj(r.b);
    C M10 = cadd(cscale(v.m10, r.a), cmul(v.m11, bc));
    C M11 = cadd(cmul(v.m10, r.b), cscale(v.m11, r.d));
    return cmul(M10, cconj(v.m10)).r + cmul(M11, cconj(v.m11)).r;
}

__global__ __launch_bounds__(64) void quanv_kernel(
    const float* __restrict__ x,   // (8,30,30,3)
    const float* __restrict__ qp,  // (4,16)
    float* __restrict__ out)       // (8,30,30,4)
{
    const int tid = blockIdx.x * 64 + threadIdx.x;   // 0..25087

    // ---- fused border zeroing (3712 elements, disjoint from interior) ----
    if (tid < 3712) {
        int e = tid & 3;
        int cb_ = tid >> 2;          // 0..927
        int bb = cb_ / 116;
        int cell = cb_ - bb * 116;
        int y, xx;
        if (cell < 30)      { y = 0;  xx = cell; }
        else if (cell < 60) { y = 29; xx = cell - 30; }
        else if (cell < 88) { xx = 0; y = cell - 59; }
        else                { xx = 29; y = cell - 87; }
        out[((bb * 30 + y) * 30 + xx) * 4 + e] = 0.0f;
    }

    // sim mapping: ch fastest for coalesced output
    const int ch = tid & 3;
    const int sidx = tid >> 2;       // 0..6271
    const int j  = sidx % 28;
    const int t1 = sidx / 28;
    const int i  = t1 % 28;
    const int b  = t1 / 28;

    // --- per-qubit RX half-angle sin/cos ---
    float cq[9], sq[9];
#pragma unroll
    for (int q = 0; q < 9; ++q) {
        int y = i + q / 3, xx = j + q % 3;
        const float* p = x + (((b * 30 + y) * 30) + xx) * 3;
        float avg = (p[0] + p[1] + p[2]) * (1.0f / 3.0f);
        __sincosf(PI_F * avg - 0.5f * PI_F, &sq[q], &cq[q]);
    }

    // --- 8 pair matrices: V[k] = RX(th[2k+1]) RZ(th[2k]) ---
    const float* th = qp + ch * 16;
    V22 V[8];
#pragma unroll
    for (int k = 0; k < 8; ++k)
        V[k] = makeV(0.5f * th[2 * k + 1], 0.5f * th[2 * k]);

    C x0, x1;

    // ================= A side: qubit 0 =================
    // pair0 (1,0): rho0 = c1^2 den(phi0) + s1^2 den(V0 phi0)
    Rho r0p = den_pure({ cq[0], 0.0f }, { 0.0f, -sq[0] });
    applyV_pure(V[0], cq[0], sq[0], x0, x1);
    Rho r0v = den_pure(x0, x1);
    float w1 = sq[1] * sq[1], w1c = 1.0f - w1;
    Rho rho0;
    rho0.a = w1c * r0p.a + w1 * r0v.a;
    rho0.d = w1c * r0p.d + w1 * r0v.d;
    rho0.b = cadd(cscale(r0p.b, w1c), cscale(r0v.b, w1));

    // pair1 (3,2): p2 = P(q2=1) = c3^2 s2^2 + s3^2 |(V1 phi2)_1|^2
    applyV_pure(V[1], cq[2], sq[2], x0, x1);
    float p2 = (cq[3] * cq[3]) * (sq[2] * sq[2])
             + (sq[3] * sq[3]) * (x1.r * x1.r + x1.i * x1.i);

    // pair2 (2,0): rho0 <- (1-p2) rho0 + p2 V2 rho0 V2†
    {
        Rho rv = applyV_rho(V[2], rho0);
        float p2c = 1.0f - p2;
        rho0.a = p2c * rho0.a + p2 * rv.a;
        rho0.d = p2c * rho0.d + p2 * rv.d;
        rho0.b = cadd(cscale(rho0.b, p2c), cscale(rv.b, p2));
    }

    // ================= B side: qubit 4 =================
    // pair4 (5,4): rho4 = c5^2 den(phi4) + s5^2 den(V4 phi4)
    Rho r4p = den_pure({ cq[4], 0.0f }, { 0.0f, -sq[4] });
    applyV_pure(V[4], cq[4], sq[4], x0, x1);
    Rho r4v = den_pure(x0, x1);
    float w5 = sq[5] * sq[5], w5c = 1.0f - w5;
    Rho rho4;
    rho4.a = w5c * r4p.a + w5 * r4v.a;
    rho4.d = w5c * r4p.d + w5 * r4v.d;
    rho4.b = cadd(cscale(r4p.b, w5c), cscale(r4v.b, w5));

    // pair3 (8,7): p7 = c8^2 s7^2 + s8^2 |(V3 phi7)_1|^2
    applyV_pure(V[3], cq[7], sq[7], x0, x1);
    float p7 = (cq[8] * cq[8]) * (sq[7] * sq[7])
             + (sq[8] * sq[8]) * (x1.r * x1.r + x1.i * x1.i);

    // pair5 (7,6): d1 = P(q6=1) = (1-p7) s6^2 + p7 |(V5 phi6)_1|^2
    applyV_pure(V[5], cq[6], sq[6], x0, x1);
    float d1 = (1.0f - p7) * (sq[6] * sq[6])
             + p7 * (x1.r * x1.r + x1.i * x1.i);

    // pair6 (6,4): p1 = P(q4=1) = (1-d1) rho4_11 + d1 (V6 rho4 V6†)_11
    float p1 = (1.0f - d1) * rho4.d + d1 * rho11_after(V[6], rho4);

    // pair7 (4,0): z = 1 - 2[(1-p1) rho0_11 + p1 (V7 rho0 V7†)_11]
    float z11U = rho11_after(V[7], rho0);
    float res = 1.0f - ((1.0f - p1) * rho0.d + p1 * z11U);   // = (z+1)/2

    out[((b * 30 + (i + 1)) * 30 + (j + 1)) * 4 + ch] = res;
}

extern "C" void kernel_launch(void* const* d_in, const int* in_sizes, int n_in,
                              void* d_out, int out_size, void* d_ws, size_t ws_size,
                              hipStream_t stream) {
    const float* x  = (const float*)d_in[0];   // (8,30,30,3) fp32
    const float* qp = (const float*)d_in[1];   // (4,16) fp32
    float* out = (float*)d_out;                // (8,30,30,4) fp32

    // 25088 sims, 1 thread each; 392 blocks x 64 spreads across CUs
    quanv_kernel<<<392, 64, 0, stream>>>(x, qp, out);
}